// Round 9
// baseline (321.309 us; speedup 1.0000x reference)
//
#include <hip/hip_runtime.h>
#include <stdint.h>
#include <float.h>

typedef _Float16 f16x8 __attribute__((ext_vector_type(8)));  // 8 f16 (4 VGPRs)
typedef float f32x4 __attribute__((ext_vector_type(4)));

#define D_DIM 256
#define K_CODES 8192
#define M_TOK 32768
#define MARGIN 0.08f

__device__ __forceinline__ void gload_lds16(const void* g, void* l) {
  __builtin_amdgcn_global_load_lds(
      (__attribute__((address_space(1))) void*)(uintptr_t)g,
      (__attribute__((address_space(3))) void*)l,
      16, 0, 0);
}

// ---------------------------------------------------------------------------
// Kernel 1: codebook fp32 -> f16 (RNE) in per-tile MFMA fragment order,
// + fp32 row norms. (proven rounds 4/5/8)
// ---------------------------------------------------------------------------
__global__ __launch_bounds__(256) void split_cb(
    const float* __restrict__ cb, char* __restrict__ c_frag,
    float* __restrict__ c_norm) {
  const int r = threadIdx.x & 31;
  const int n = blockIdx.x * 8 + (threadIdx.x >> 5);
  const int k0 = r * 8;
  f32x4 p0 = *(const f32x4*)(cb + n * D_DIM + k0);
  f32x4 p1 = *(const f32x4*)(cb + n * D_DIM + k0 + 4);
  f16x8 h;
  float ns = 0.f;
#pragma unroll
  for (int j = 0; j < 4; ++j) {
    ns = fmaf(p0[j], p0[j], ns);
    h[j] = (_Float16)p0[j];
  }
#pragma unroll
  for (int j = 0; j < 4; ++j) {
    ns = fmaf(p1[j], p1[j], ns);
    h[4 + j] = (_Float16)p1[j];
  }
  const int kk = r >> 2, g = r & 3;
  const int tile = n >> 6, ct = (n >> 4) & 3, lrow = n & 15;
  *(f16x8*)(c_frag + tile * 32768 + (kk * 4 + ct) * 1024 + (g * 16 + lrow) * 16) = h;
#pragma unroll
  for (int m = 16; m > 0; m >>= 1) ns += __shfl_xor(ns, m);
  if (r == 0) c_norm[n] = ns;
}

// ---------------------------------------------------------------------------
// Kernel 2: MFMA distance + per-token top-2, half-tile pipeline + WAVE
// PHASE-STAGGER: half the waves run {TOP2H; MFMA_HALF}, half {MFMA_HALF;
// TOP2H} between the same barriers, so each SIMD always has one wave feeding
// the MFMA pipe and one in VALU (m114: cross-wave pipe overlap = max).
// Grid 256 = 128 row-groups x 2 code-sets; 512 thr (8 waves), 1 block/CU.
// Score = c_norm[n] - 2*(x_h+x_l).c_h   (x_norm dropped: row-constant)
// ---------------------------------------------------------------------------
#define STAGE(BUF, TT)                                                         \
  do {                                                                         \
    const char* _src = c_frag + (size_t)(TT) * 32768;                          \
    _Pragma("unroll") for (int _i = 0; _i < 4; ++_i)                           \
        gload_lds16(_src + _i * 8192 + t * 16, (BUF) + _i * 8192 + w * 1024);  \
  } while (0)

// first hi-MFMA of each chain takes the hoisted zero C-in (kills per-tile
// acc zero-init VALU); remaining 7 kk accumulate.
#define MFMA_HALF(FB, C0, ACC)                                                 \
  do {                                                                         \
    {                                                                          \
      f16x8 _b0 = *(const f16x8*)((FB) + (0 * 4 + (C0)) * 1024);               \
      f16x8 _b1 = *(const f16x8*)((FB) + (0 * 4 + (C0) + 1) * 1024);           \
      ACC[0][0] = __builtin_amdgcn_mfma_f32_16x16x32_f16(a_hi[0][0], _b0, kz4, 0, 0, 0); \
      ACC[1][0] = __builtin_amdgcn_mfma_f32_16x16x32_f16(a_hi[1][0], _b0, kz4, 0, 0, 0); \
      ACC[0][1] = __builtin_amdgcn_mfma_f32_16x16x32_f16(a_hi[0][0], _b1, kz4, 0, 0, 0); \
      ACC[1][1] = __builtin_amdgcn_mfma_f32_16x16x32_f16(a_hi[1][0], _b1, kz4, 0, 0, 0); \
      ACC[0][0] = __builtin_amdgcn_mfma_f32_16x16x32_f16(a_lo[0][0], _b0, ACC[0][0], 0, 0, 0); \
      ACC[1][0] = __builtin_amdgcn_mfma_f32_16x16x32_f16(a_lo[1][0], _b0, ACC[1][0], 0, 0, 0); \
      ACC[0][1] = __builtin_amdgcn_mfma_f32_16x16x32_f16(a_lo[0][0], _b1, ACC[0][1], 0, 0, 0); \
      ACC[1][1] = __builtin_amdgcn_mfma_f32_16x16x32_f16(a_lo[1][0], _b1, ACC[1][1], 0, 0, 0); \
    }                                                                          \
    _Pragma("unroll") for (int _kk = 1; _kk < 8; ++_kk) {                      \
      f16x8 _b0 = *(const f16x8*)((FB) + (_kk * 4 + (C0)) * 1024);             \
      f16x8 _b1 = *(const f16x8*)((FB) + (_kk * 4 + (C0) + 1) * 1024);         \
      ACC[0][0] = __builtin_amdgcn_mfma_f32_16x16x32_f16(a_hi[0][_kk], _b0, ACC[0][0], 0, 0, 0); \
      ACC[1][0] = __builtin_amdgcn_mfma_f32_16x16x32_f16(a_hi[1][_kk], _b0, ACC[1][0], 0, 0, 0); \
      ACC[0][1] = __builtin_amdgcn_mfma_f32_16x16x32_f16(a_hi[0][_kk], _b1, ACC[0][1], 0, 0, 0); \
      ACC[1][1] = __builtin_amdgcn_mfma_f32_16x16x32_f16(a_hi[1][_kk], _b1, ACC[1][1], 0, 0, 0); \
      ACC[0][0] = __builtin_amdgcn_mfma_f32_16x16x32_f16(a_lo[0][_kk], _b0, ACC[0][0], 0, 0, 0); \
      ACC[1][0] = __builtin_amdgcn_mfma_f32_16x16x32_f16(a_lo[1][_kk], _b0, ACC[1][0], 0, 0, 0); \
      ACC[0][1] = __builtin_amdgcn_mfma_f32_16x16x32_f16(a_lo[0][_kk], _b1, ACC[0][1], 0, 0, 0); \
      ACC[1][1] = __builtin_amdgcn_mfma_f32_16x16x32_f16(a_lo[1][_kk], _b1, ACC[1][1], 0, 0, 0); \
    }                                                                          \
  } while (0)

#define LOADCN2(C0V, C1V, N0H)                                                 \
  do {                                                                         \
    C0V = c_norm[(N0H) + lrow];                                                \
    C1V = c_norm[(N0H) + 16 + lrow];                                           \
  } while (0)

// min over the 2 ct candidates, then top-2 update (strict < keeps first-min;
// ct tie keeps lower index; halves/tiles ascend n, so ordering is preserved)
#define TOP2H(ACC, CN0, CN1, N0H)                                              \
  do {                                                                         \
    const int _nb = (N0H) + lrow;                                              \
    _Pragma("unroll") for (int _rb = 0; _rb < 2; ++_rb)                        \
        _Pragma("unroll") for (int _j = 0; _j < 4; ++_j) {                     \
      float _s0 = fmaf(-2.f, ACC[_rb][0][_j], (CN0));                          \
      float _s1 = fmaf(-2.f, ACC[_rb][1][_j], (CN1));                          \
      float _mm = fminf(_s0, _s1);                                             \
      int _n = _nb + ((_s1 < _s0) ? 16 : 0);                                   \
      bool _lt1 = _mm < bs1[_rb][_j];                                          \
      bool _lt2 = _mm < bs2[_rb][_j];                                          \
      bs2[_rb][_j] = _lt1 ? bs1[_rb][_j] : (_lt2 ? _mm : bs2[_rb][_j]);        \
      bi2[_rb][_j] = _lt1 ? bi1[_rb][_j] : (_lt2 ? _n : bi2[_rb][_j]);         \
      bs1[_rb][_j] = _lt1 ? _mm : bs1[_rb][_j];                                \
      bi1[_rb][_j] = _lt1 ? _n : bi1[_rb][_j];                                 \
    }                                                                          \
  } while (0)

__global__ __launch_bounds__(512) __attribute__((amdgpu_waves_per_eu(2, 2)))
void vq_main(
    const float* __restrict__ x, const char* __restrict__ c_frag,
    const float* __restrict__ c_norm,
    float* __restrict__ out_s1, float* __restrict__ out_s2,
    int* __restrict__ out_i1, int* __restrict__ out_i2) {
  __shared__ char smem[65536];
  const int t = threadIdx.x;
  const int w = t >> 6, l = t & 63;
  const int lrow = l & 15, lg = l >> 4;
  const int stg = (w ^ (w >> 2)) & 1;   // per-SIMD phase-stagger bit
  const int cs = blockIdx.x >> 7;       // code-set (0/1)
  const int rg = blockIdx.x & 127;      // row-group
  const int row0 = rg * 256 + w * 32;   // wave's 32 rows
  const int tile0 = cs * 64;            // 64 tiles (4096 codes) per code-set
  const f32x4 kz4 = {0.f, 0.f, 0.f, 0.f};

  // A fragments: 32 rows x 256 k, f16 hi+lo, in registers (128 VGPR).
  f16x8 a_hi[2][8], a_lo[2][8];
#pragma unroll
  for (int rb = 0; rb < 2; ++rb) {
    const float* xr = x + (size_t)(row0 + rb * 16 + lrow) * D_DIM;
#pragma unroll
    for (int kk = 0; kk < 8; ++kk) {
      f32x4 p0 = *(const f32x4*)(xr + kk * 32 + lg * 8);
      f32x4 p1 = *(const f32x4*)(xr + kk * 32 + lg * 8 + 4);
      float v[8];
#pragma unroll
      for (int j = 0; j < 4; ++j) { v[j] = p0[j]; v[j + 4] = p1[j]; }
#pragma unroll
      for (int j = 0; j < 8; ++j) {
        _Float16 h = (_Float16)v[j];
        a_hi[rb][kk][j] = h;
        a_lo[rb][kk][j] = (_Float16)(v[j] - (float)h);
      }
    }
  }

  float bs1[2][4], bs2[2][4];
  int bi1[2][4], bi2[2][4];
#pragma unroll
  for (int rb = 0; rb < 2; ++rb)
#pragma unroll
    for (int j = 0; j < 4; ++j) {
      bs1[rb][j] = FLT_MAX; bs2[rb][j] = FLT_MAX;
      bi1[rb][j] = 0; bi2[rb][j] = 0;
    }

  char* sA = smem;
  char* sB = smem + 32768;
  const char* fbA = sA + l * 16;
  const char* fbB = sB + l * 16;

  f32x4 accX[2][2], accY[2][2];
  float cnX0, cnX1, cnY0, cnY1;
  int n0X, n0Y;

  // prologue: tile0 ready; prefetch tile0+1; MFMA pair0 of tile0 -> accX
  STAGE(sA, tile0);
  __syncthreads();
  STAGE(sB, tile0 + 1);
  n0X = tile0 * 64;
  LOADCN2(cnX0, cnX1, n0X);
  MFMA_HALF(fbA, 0, accX);

#pragma clang loop unroll(disable)
  for (int tt = 0; tt < 63; ++tt) {
    const char* cur = (tt & 1) ? fbB : fbA;
    char* curbuf = (tt & 1) ? sB : sA;
    const char* oth = (tt & 1) ? fbA : fbB;
    // slot 1: MFMA pair1 of tile tt -> accY ; TOP2 of pair0 (accX).
    // stagger: half the waves VALU-first so MFMA+VALU pipes overlap per SIMD.
    n0Y = (tile0 + tt) * 64 + 32;
    LOADCN2(cnY0, cnY1, n0Y);
    if (stg) {
      TOP2H(accX, cnX0, cnX1, n0X);
      MFMA_HALF(cur, 2, accY);
    } else {
      MFMA_HALF(cur, 2, accY);
      TOP2H(accX, cnX0, cnX1, n0X);
    }
    __syncthreads();  // drains stage(tt+1) into oth; cur buffer now free
    if (tt < 62) STAGE(curbuf, tile0 + tt + 2);
    // slot 2: MFMA pair0 of tile tt+1 -> accX ; TOP2 of pair1 (accY)
    n0X = (tile0 + tt + 1) * 64;
    LOADCN2(cnX0, cnX1, n0X);
    if (stg) {
      TOP2H(accY, cnY0, cnY1, n0Y);
      MFMA_HALF(oth, 0, accX);
    } else {
      MFMA_HALF(oth, 0, accX);
      TOP2H(accY, cnY0, cnY1, n0Y);
    }
  }
  // epilogue: tile 63 (odd -> fbB) pair1 -> accY ; flush both
  n0Y = (tile0 + 63) * 64 + 32;
  LOADCN2(cnY0, cnY1, n0Y);
  MFMA_HALF(fbB, 2, accY);
  TOP2H(accX, cnX0, cnX1, n0X);
  TOP2H(accY, cnY0, cnY1, n0Y);

  // merge top-2 sets across the 16 lanes (lane bits 0..3) sharing each token
#pragma unroll
  for (int m = 8; m >= 1; m >>= 1) {
#pragma unroll
    for (int rb = 0; rb < 2; ++rb)
#pragma unroll
      for (int j = 0; j < 4; ++j) {
        float u1 = __shfl_xor(bs1[rb][j], m);
        float u2 = __shfl_xor(bs2[rb][j], m);
        int v1 = __shfl_xor(bi1[rb][j], m);
        int v2 = __shfl_xor(bi2[rb][j], m);
        bool take = (u1 < bs1[rb][j]) || (u1 == bs1[rb][j] && v1 < bi1[rb][j]);
        if (take) {
          bool oldFirst = (bs1[rb][j] < u2) || (bs1[rb][j] == u2 && bi1[rb][j] < v2);
          bs2[rb][j] = oldFirst ? bs1[rb][j] : u2;
          bi2[rb][j] = oldFirst ? bi1[rb][j] : v2;
          bs1[rb][j] = u1; bi1[rb][j] = v1;
        } else {
          bool rep = (u1 < bs2[rb][j]) || (u1 == bs2[rb][j] && v1 < bi2[rb][j]);
          bs2[rb][j] = rep ? u1 : bs2[rb][j];
          bi2[rb][j] = rep ? v1 : bi2[rb][j];
        }
      }
  }
  if (lrow == 0) {
#pragma unroll
    for (int rb = 0; rb < 2; ++rb)
#pragma unroll
      for (int j = 0; j < 4; ++j) {
        const int tok = row0 + rb * 16 + lg * 4 + j;
        const int o = cs * M_TOK + tok;
        out_s1[o] = bs1[rb][j];
        out_s2[o] = bs2[rb][j];
        out_i1[o] = bi1[rb][j];
        out_i2[o] = bi2[rb][j];
      }
  }
}

// ---------------------------------------------------------------------------
// Kernel 3 (fused merge+gather): merge 2 code-sets' top-2; wave-parallel fp64
// rescore if margin small; emit x + (q - x) in fp32 (bitwise-match STE).
// ---------------------------------------------------------------------------
__global__ __launch_bounds__(256) void vq_finish(
    const float* __restrict__ s1a, const float* __restrict__ s2a,
    const int* __restrict__ i1a, const int* __restrict__ i2a,
    const float* __restrict__ x, const float* __restrict__ cb,
    float* __restrict__ out) {
  const int w = threadIdx.x >> 6, l = threadIdx.x & 63;
  const int tk = blockIdx.x * 4 + w;

  float csc[4]; int cid[4];
  csc[0] = s1a[tk];         cid[0] = i1a[tk];
  csc[1] = s2a[tk];         cid[1] = i2a[tk];
  csc[2] = s1a[M_TOK + tk]; cid[2] = i1a[M_TOK + tk];
  csc[3] = s2a[M_TOK + tk]; cid[3] = i2a[M_TOK + tk];
  float b1 = FLT_MAX, b2 = FLT_MAX;
  int j1 = 0;
#pragma unroll
  for (int c = 0; c < 4; ++c) {
    float s = csc[c]; int n = cid[c];
    bool t1 = (s < b1) || (s == b1 && n < j1);
    bool t2 = (s < b2);
    b2 = t1 ? b1 : (t2 ? s : b2);
    b1 = t1 ? s : b1;
    j1 = t1 ? n : j1;
  }
  int pick = j1;
  if (b2 - b1 < MARGIN) {  // wave-uniform
    const float* xr = x + (size_t)tk * D_DIM;
    double dc[4];
#pragma unroll
    for (int c = 0; c < 4; ++c) {
      const float* cp = cb + (size_t)cid[c] * D_DIM;
      double s = 0.0;
#pragma unroll
      for (int q = 0; q < 4; ++q) {
        const int dd = q * 64 + l;
        double e = (double)xr[dd] - (double)cp[dd];
        s = fma(e, e, s);
      }
      dc[c] = s;
    }
#pragma unroll
    for (int m = 32; m > 0; m >>= 1)
#pragma unroll
      for (int c = 0; c < 4; ++c) dc[c] += __shfl_xor(dc[c], m);
    double bd = DBL_MAX; int bj = INT32_MAX;
#pragma unroll
    for (int c = 0; c < 4; ++c)
      if (dc[c] < bd || (dc[c] == bd && cid[c] < bj)) { bd = dc[c]; bj = cid[c]; }
    pick = bj;
  }
  f32x4 q = *(const f32x4*)(cb + (size_t)pick * D_DIM + l * 4);
  f32x4 xv = *(const f32x4*)(x + (size_t)tk * D_DIM + l * 4);
  f32x4 o;
#pragma unroll
  for (int j = 0; j < 4; ++j) o[j] = xv[j] + (q[j] - xv[j]);
  *(f32x4*)(out + (size_t)tk * D_DIM + l * 4) = o;
}

extern "C" void kernel_launch(void* const* d_in, const int* in_sizes, int n_in,
                              void* d_out, int out_size, void* d_ws, size_t ws_size,
                              hipStream_t stream) {
  const float* x = (const float*)d_in[0];    // [8,4096,256] fp32
  const float* cbk = (const float*)d_in[1];  // [8192,256] fp32
  float* out = (float*)d_out;                // [8,4096,256] fp32
  char* ws = (char*)d_ws;
  // ws: c_frag 4M | c_norm 32K (pad 64K) | s1 256K | s2 256K | i1 256K | i2 256K
  char* c_frag = ws;
  float* c_norm = (float*)(ws + (4u << 20));
  char* cand = ws + (4u << 20) + (64u << 10);
  float* s1 = (float*)(cand);
  float* s2 = (float*)(cand + (256u << 10));
  int* i1 = (int*)(cand + (512u << 10));
  int* i2 = (int*)(cand + (768u << 10));

  split_cb<<<K_CODES / 8, 256, 0, stream>>>(cbk, c_frag, c_norm);
  vq_main<<<256, 512, 0, stream>>>(x, c_frag, c_norm, s1, s2, i1, i2);
  vq_finish<<<M_TOK / 4, 256, 0, stream>>>(s1, s2, i1, i2, x, cbk, out);
}

// Round 10
// 252.079 us; speedup vs baseline: 1.2746x; 1.2746x over previous
//
#include <hip/hip_runtime.h>
#include <stdint.h>
#include <float.h>

typedef _Float16 f16x8 __attribute__((ext_vector_type(8)));  // 8 f16 (4 VGPRs)
typedef float f32x4 __attribute__((ext_vector_type(4)));

#define D_DIM 256
#define K_CODES 8192
#define M_TOK 32768
#define MARGIN 0.08f

__device__ __forceinline__ void gload_lds16(const void* g, void* l) {
  __builtin_amdgcn_global_load_lds(
      (__attribute__((address_space(1))) void*)(uintptr_t)g,
      (__attribute__((address_space(3))) void*)l,
      16, 0, 0);
}

// ---------------------------------------------------------------------------
// Kernel 1: codebook fp32 -> f16 (RNE) in per-tile MFMA fragment order,
// + fp32 row norms. (proven rounds 4/5/8/9)
// ---------------------------------------------------------------------------
__global__ __launch_bounds__(256) void split_cb(
    const float* __restrict__ cb, char* __restrict__ c_frag,
    float* __restrict__ c_norm) {
  const int r = threadIdx.x & 31;
  const int n = blockIdx.x * 8 + (threadIdx.x >> 5);
  const int k0 = r * 8;
  f32x4 p0 = *(const f32x4*)(cb + n * D_DIM + k0);
  f32x4 p1 = *(const f32x4*)(cb + n * D_DIM + k0 + 4);
  f16x8 h;
  float ns = 0.f;
#pragma unroll
  for (int j = 0; j < 4; ++j) {
    ns = fmaf(p0[j], p0[j], ns);
    h[j] = (_Float16)p0[j];
  }
#pragma unroll
  for (int j = 0; j < 4; ++j) {
    ns = fmaf(p1[j], p1[j], ns);
    h[4 + j] = (_Float16)p1[j];
  }
  const int kk = r >> 2, g = r & 3;
  const int tile = n >> 6, ct = (n >> 4) & 3, lrow = n & 15;
  *(f16x8*)(c_frag + tile * 32768 + (kk * 4 + ct) * 1024 + (g * 16 + lrow) * 16) = h;
#pragma unroll
  for (int m = 16; m > 0; m >>= 1) ns += __shfl_xor(ns, m);
  if (r == 0) c_norm[n] = ns;
}

// ---------------------------------------------------------------------------
// Kernel 2: MFMA distance + per-token top-2. HI-ONLY scan (single f16 on
// both sides): score noise sigma ~6.5e-3 << MARGIN 0.08; fp64 rescue in
// vq_finish repairs near-ties. Halves MFMA work vs rounds 4-9.
// Half-tile double-acc pipeline: MFMA(half h) overlaps TOP2(half h-1).
// Grid 512 = 256 row-groups x 2 code-sets; 256 thr (4 waves), 2 blocks/CU.
// T5: s_setprio(1) around MFMA cluster.
// Score = c_norm[n] - 2*x_h.c_h   (x_norm dropped: row-constant)
// ---------------------------------------------------------------------------
#define STAGE(BUF, TT)                                                         \
  do {                                                                         \
    const char* _src = c_frag + (size_t)(TT) * 32768;                          \
    _Pragma("unroll") for (int _i = 0; _i < 8; ++_i)                           \
        gload_lds16(_src + _i * 4096 + t * 16, (BUF) + _i * 4096 + w * 1024);  \
  } while (0)

// hi-only: 8 kk x {2 ds_read_b128, 4 MFMA}; kk=0 takes hoisted zero C-in.
#define MFMA_HALF(FB, C0, ACC)                                                 \
  do {                                                                         \
    __builtin_amdgcn_s_setprio(1);                                             \
    {                                                                          \
      f16x8 _b0 = *(const f16x8*)((FB) + (0 * 4 + (C0)) * 1024);               \
      f16x8 _b1 = *(const f16x8*)((FB) + (0 * 4 + (C0) + 1) * 1024);           \
      ACC[0][0] = __builtin_amdgcn_mfma_f32_16x16x32_f16(a_hi[0][0], _b0, kz4, 0, 0, 0); \
      ACC[1][0] = __builtin_amdgcn_mfma_f32_16x16x32_f16(a_hi[1][0], _b0, kz4, 0, 0, 0); \
      ACC[0][1] = __builtin_amdgcn_mfma_f32_16x16x32_f16(a_hi[0][0], _b1, kz4, 0, 0, 0); \
      ACC[1][1] = __builtin_amdgcn_mfma_f32_16x16x32_f16(a_hi[1][0], _b1, kz4, 0, 0, 0); \
    }                                                                          \
    _Pragma("unroll") for (int _kk = 1; _kk < 8; ++_kk) {                      \
      f16x8 _b0 = *(const f16x8*)((FB) + (_kk * 4 + (C0)) * 1024);             \
      f16x8 _b1 = *(const f16x8*)((FB) + (_kk * 4 + (C0) + 1) * 1024);         \
      ACC[0][0] = __builtin_amdgcn_mfma_f32_16x16x32_f16(a_hi[0][_kk], _b0, ACC[0][0], 0, 0, 0); \
      ACC[1][0] = __builtin_amdgcn_mfma_f32_16x16x32_f16(a_hi[1][_kk], _b0, ACC[1][0], 0, 0, 0); \
      ACC[0][1] = __builtin_amdgcn_mfma_f32_16x16x32_f16(a_hi[0][_kk], _b1, ACC[0][1], 0, 0, 0); \
      ACC[1][1] = __builtin_amdgcn_mfma_f32_16x16x32_f16(a_hi[1][_kk], _b1, ACC[1][1], 0, 0, 0); \
    }                                                                          \
    __builtin_amdgcn_s_setprio(0);                                             \
  } while (0)

#define LOADCN2(C0V, C1V, N0H)                                                 \
  do {                                                                         \
    C0V = c_norm[(N0H) + lrow];                                                \
    C1V = c_norm[(N0H) + 16 + lrow];                                           \
  } while (0)

// min over the 2 ct candidates, then top-2 update (strict < keeps first-min;
// ct tie keeps lower index; halves/tiles ascend n, so ordering is preserved)
#define TOP2H(ACC, CN0, CN1, N0H)                                              \
  do {                                                                         \
    const int _nb = (N0H) + lrow;                                              \
    _Pragma("unroll") for (int _rb = 0; _rb < 2; ++_rb)                        \
        _Pragma("unroll") for (int _j = 0; _j < 4; ++_j) {                     \
      float _s0 = fmaf(-2.f, ACC[_rb][0][_j], (CN0));                          \
      float _s1 = fmaf(-2.f, ACC[_rb][1][_j], (CN1));                          \
      float _mm = fminf(_s0, _s1);                                             \
      int _n = _nb + ((_s1 < _s0) ? 16 : 0);                                   \
      bool _lt1 = _mm < bs1[_rb][_j];                                          \
      bool _lt2 = _mm < bs2[_rb][_j];                                          \
      bs2[_rb][_j] = _lt1 ? bs1[_rb][_j] : (_lt2 ? _mm : bs2[_rb][_j]);        \
      bi2[_rb][_j] = _lt1 ? bi1[_rb][_j] : (_lt2 ? _n : bi2[_rb][_j]);         \
      bs1[_rb][_j] = _lt1 ? _mm : bs1[_rb][_j];                                \
      bi1[_rb][_j] = _lt1 ? _n : bi1[_rb][_j];                                 \
    }                                                                          \
  } while (0)

__global__ __launch_bounds__(256) __attribute__((amdgpu_waves_per_eu(2, 2)))
void vq_main(
    const float* __restrict__ x, const char* __restrict__ c_frag,
    const float* __restrict__ c_norm,
    float* __restrict__ out_s1, float* __restrict__ out_s2,
    int* __restrict__ out_i1, int* __restrict__ out_i2) {
  __shared__ char smem[65536];
  const int t = threadIdx.x;
  const int w = t >> 6, l = t & 63;
  const int lrow = l & 15, lg = l >> 4;
  const int cs = blockIdx.x & 1;        // code-set (0/1)
  const int rg = blockIdx.x >> 1;       // row-group
  const int row0 = rg * 128 + w * 32;   // wave's 32 rows
  const int tile0 = cs * 64;            // 64 tiles (4096 codes) per code-set
  const f32x4 kz4 = {0.f, 0.f, 0.f, 0.f};

  // A fragments: 32 rows x 256 k, single f16 (64 VGPR).
  f16x8 a_hi[2][8];
#pragma unroll
  for (int rb = 0; rb < 2; ++rb) {
    const float* xr = x + (size_t)(row0 + rb * 16 + lrow) * D_DIM;
#pragma unroll
    for (int kk = 0; kk < 8; ++kk) {
      f32x4 p0 = *(const f32x4*)(xr + kk * 32 + lg * 8);
      f32x4 p1 = *(const f32x4*)(xr + kk * 32 + lg * 8 + 4);
#pragma unroll
      for (int j = 0; j < 4; ++j) {
        a_hi[rb][kk][j] = (_Float16)p0[j];      // RNE
        a_hi[rb][kk][4 + j] = (_Float16)p1[j];
      }
    }
  }

  float bs1[2][4], bs2[2][4];
  int bi1[2][4], bi2[2][4];
#pragma unroll
  for (int rb = 0; rb < 2; ++rb)
#pragma unroll
    for (int j = 0; j < 4; ++j) {
      bs1[rb][j] = FLT_MAX; bs2[rb][j] = FLT_MAX;
      bi1[rb][j] = 0; bi2[rb][j] = 0;
    }

  char* sA = smem;
  char* sB = smem + 32768;
  const char* fbA = sA + l * 16;
  const char* fbB = sB + l * 16;

  f32x4 accX[2][2], accY[2][2];
  float cnX0, cnX1, cnY0, cnY1;
  int n0X, n0Y;

  // prologue: tile0 ready; prefetch tile0+1; MFMA pair0 of tile0 -> accX
  STAGE(sA, tile0);
  __syncthreads();
  STAGE(sB, tile0 + 1);
  n0X = tile0 * 64;
  LOADCN2(cnX0, cnX1, n0X);
  MFMA_HALF(fbA, 0, accX);

#pragma clang loop unroll(disable)
  for (int tt = 0; tt < 63; ++tt) {
    const char* cur = (tt & 1) ? fbB : fbA;
    char* curbuf = (tt & 1) ? sB : sA;
    const char* oth = (tt & 1) ? fbA : fbB;
    // slot 1: MFMA pair1 of tile tt -> accY ; TOP2 of pair0 (accX)
    n0Y = (tile0 + tt) * 64 + 32;
    LOADCN2(cnY0, cnY1, n0Y);
    MFMA_HALF(cur, 2, accY);
    TOP2H(accX, cnX0, cnX1, n0X);
    __syncthreads();  // drains stage(tt+1) into oth; cur buffer now free
    if (tt < 62) STAGE(curbuf, tile0 + tt + 2);
    // slot 2: MFMA pair0 of tile tt+1 -> accX ; TOP2 of pair1 (accY)
    n0X = (tile0 + tt + 1) * 64;
    LOADCN2(cnX0, cnX1, n0X);
    MFMA_HALF(oth, 0, accX);
    TOP2H(accY, cnY0, cnY1, n0Y);
  }
  // epilogue: tile 63 (odd -> fbB) pair1 -> accY ; flush both
  n0Y = (tile0 + 63) * 64 + 32;
  LOADCN2(cnY0, cnY1, n0Y);
  MFMA_HALF(fbB, 2, accY);
  TOP2H(accX, cnX0, cnX1, n0X);
  TOP2H(accY, cnY0, cnY1, n0Y);

  // merge top-2 sets across the 16 lanes (lane bits 0..3) sharing each token
#pragma unroll
  for (int m = 8; m >= 1; m >>= 1) {
#pragma unroll
    for (int rb = 0; rb < 2; ++rb)
#pragma unroll
      for (int j = 0; j < 4; ++j) {
        float u1 = __shfl_xor(bs1[rb][j], m);
        float u2 = __shfl_xor(bs2[rb][j], m);
        int v1 = __shfl_xor(bi1[rb][j], m);
        int v2 = __shfl_xor(bi2[rb][j], m);
        bool take = (u1 < bs1[rb][j]) || (u1 == bs1[rb][j] && v1 < bi1[rb][j]);
        if (take) {
          bool oldFirst = (bs1[rb][j] < u2) || (bs1[rb][j] == u2 && bi1[rb][j] < v2);
          bs2[rb][j] = oldFirst ? bs1[rb][j] : u2;
          bi2[rb][j] = oldFirst ? bi1[rb][j] : v2;
          bs1[rb][j] = u1; bi1[rb][j] = v1;
        } else {
          bool rep = (u1 < bs2[rb][j]) || (u1 == bs2[rb][j] && v1 < bi2[rb][j]);
          bs2[rb][j] = rep ? u1 : bs2[rb][j];
          bi2[rb][j] = rep ? v1 : bi2[rb][j];
        }
      }
  }
  if (lrow == 0) {
#pragma unroll
    for (int rb = 0; rb < 2; ++rb)
#pragma unroll
      for (int j = 0; j < 4; ++j) {
        const int tok = row0 + rb * 16 + lg * 4 + j;
        const int o = cs * M_TOK + tok;
        out_s1[o] = bs1[rb][j];
        out_s2[o] = bs2[rb][j];
        out_i1[o] = bi1[rb][j];
        out_i2[o] = bi2[rb][j];
      }
  }
}

// ---------------------------------------------------------------------------
// Kernel 3 (fused merge+gather): merge 2 code-sets' top-2; wave-parallel fp64
// rescore if margin small; emit x + (q - x) in fp32 (bitwise-match STE).
// ---------------------------------------------------------------------------
__global__ __launch_bounds__(256) void vq_finish(
    const float* __restrict__ s1a, const float* __restrict__ s2a,
    const int* __restrict__ i1a, const int* __restrict__ i2a,
    const float* __restrict__ x, const float* __restrict__ cb,
    float* __restrict__ out) {
  const int w = threadIdx.x >> 6, l = threadIdx.x & 63;
  const int tk = blockIdx.x * 4 + w;

  float csc[4]; int cid[4];
  csc[0] = s1a[tk];         cid[0] = i1a[tk];
  csc[1] = s2a[tk];         cid[1] = i2a[tk];
  csc[2] = s1a[M_TOK + tk]; cid[2] = i1a[M_TOK + tk];
  csc[3] = s2a[M_TOK + tk]; cid[3] = i2a[M_TOK + tk];
  float b1 = FLT_MAX, b2 = FLT_MAX;
  int j1 = 0;
#pragma unroll
  for (int c = 0; c < 4; ++c) {
    float s = csc[c]; int n = cid[c];
    bool t1 = (s < b1) || (s == b1 && n < j1);
    bool t2 = (s < b2);
    b2 = t1 ? b1 : (t2 ? s : b2);
    b1 = t1 ? s : b1;
    j1 = t1 ? n : j1;
  }
  int pick = j1;
  if (b2 - b1 < MARGIN) {  // wave-uniform
    const float* xr = x + (size_t)tk * D_DIM;
    double dc[4];
#pragma unroll
    for (int c = 0; c < 4; ++c) {
      const float* cp = cb + (size_t)cid[c] * D_DIM;
      double s = 0.0;
#pragma unroll
      for (int q = 0; q < 4; ++q) {
        const int dd = q * 64 + l;
        double e = (double)xr[dd] - (double)cp[dd];
        s = fma(e, e, s);
      }
      dc[c] = s;
    }
#pragma unroll
    for (int m = 32; m > 0; m >>= 1)
#pragma unroll
      for (int c = 0; c < 4; ++c) dc[c] += __shfl_xor(dc[c], m);
    double bd = DBL_MAX; int bj = INT32_MAX;
#pragma unroll
    for (int c = 0; c < 4; ++c)
      if (dc[c] < bd || (dc[c] == bd && cid[c] < bj)) { bd = dc[c]; bj = cid[c]; }
    pick = bj;
  }
  f32x4 q = *(const f32x4*)(cb + (size_t)pick * D_DIM + l * 4);
  f32x4 xv = *(const f32x4*)(x + (size_t)tk * D_DIM + l * 4);
  f32x4 o;
#pragma unroll
  for (int j = 0; j < 4; ++j) o[j] = xv[j] + (q[j] - xv[j]);
  *(f32x4*)(out + (size_t)tk * D_DIM + l * 4) = o;
}

extern "C" void kernel_launch(void* const* d_in, const int* in_sizes, int n_in,
                              void* d_out, int out_size, void* d_ws, size_t ws_size,
                              hipStream_t stream) {
  const float* x = (const float*)d_in[0];    // [8,4096,256] fp32
  const float* cbk = (const float*)d_in[1];  // [8192,256] fp32
  float* out = (float*)d_out;                // [8,4096,256] fp32
  char* ws = (char*)d_ws;
  // ws: c_frag 4M | c_norm 32K (pad 64K) | s1 256K | s2 256K | i1 256K | i2 256K
  char* c_frag = ws;
  float* c_norm = (float*)(ws + (4u << 20));
  char* cand = ws + (4u << 20) + (64u << 10);
  float* s1 = (float*)(cand);
  float* s2 = (float*)(cand + (256u << 10));
  int* i1 = (int*)(cand + (512u << 10));
  int* i2 = (int*)(cand + (768u << 10));

  split_cb<<<K_CODES / 8, 256, 0, stream>>>(cbk, c_frag, c_norm);
  vq_main<<<512, 256, 0, stream>>>(x, c_frag, c_norm, s1, s2, i1, i2);
  vq_finish<<<M_TOK / 4, 256, 0, stream>>>(s1, s2, i1, i2, x, cbk, out);
}